// Round 1
// 937.534 us; speedup vs baseline: 1.0044x; 1.0044x over previous
//
#include <hip/hip_runtime.h>
#include <math.h>

// CCALayer3D: x[4,64,32,128,128] fp32
//   y[b,c]  = std(x[b,c]) + mean(x[b,c])        (biased std over spatial)
//   h       = relu(w1 @ y + b1)                 w1:[4,64]
//   g       = sigmoid(w2 @ h + b2)              w2:[64,4]
//   out     = x * g[b,c]
// Memory-bound: 512MiB read (stats) + 512MiB read + 512MiB write (scale)
// ~1.61 GB => ~256 us floor at 6.3 TB/s.
//
// This version vs previous (941.5 us):
//  - no hipMemsetAsync, no double atomics: stats writes disjoint double2
//    partials; MLP kernel reduces the 16 partials per channel (64 KB).
//  - stats loop: explicit 4-load pipeline, 2 independent accumulator pairs.
//  - scale pass traverses x in REVERSE block order to harvest the tail of x
//    still resident in the 256 MiB Infinity Cache after the stats pass
//    (same-order traversal is LRU worst case: 0 hits).
//  - out written with non-temporal stores (write-once stream; don't evict x).

#define CCH 64
#define BATCH 4
#define NCH (BATCH * CCH)            // 256 channels
#define SPATIAL (32 * 128 * 128)     // 524288 elements per channel
#define NVEC (SPATIAL / 4)           // 131072 float4 per channel

#define BPC1 16                      // blocks per channel, stats kernel
#define BPC3 64                      // blocks per channel, scale kernel

typedef float vfloat4 __attribute__((ext_vector_type(4)));

// ---------------- Kernel 1: per-channel partial sum & sumsq ----------------
// grid = NCH*BPC1 blocks x 256 threads. Each thread: 32 float4 loads.
// Each block writes its own double2 partial -- no memset, no atomics.
__global__ __launch_bounds__(256) void cca_stats(const float* __restrict__ x,
                                                 double2* __restrict__ part) {
    const int bc  = blockIdx.x / BPC1;
    const int blk = blockIdx.x % BPC1;
    const float4* p = (const float4*)(x + (size_t)bc * SPATIAL)
                    + (size_t)blk * (NVEC / BPC1) + threadIdx.x;

    // 32 float4 per thread, 4 loads in flight, 2 independent accum pairs.
    float s1a = 0.f, s2a = 0.f, s1b = 0.f, s2b = 0.f;
    #pragma unroll
    for (int k = 0; k < 32; k += 4) {
        float4 v0 = p[(k + 0) * 256];
        float4 v1 = p[(k + 1) * 256];
        float4 v2 = p[(k + 2) * 256];
        float4 v3 = p[(k + 3) * 256];
        s1a += (v0.x + v0.y) + (v0.z + v0.w);
        s2a += (v0.x * v0.x + v0.y * v0.y) + (v0.z * v0.z + v0.w * v0.w);
        s1b += (v1.x + v1.y) + (v1.z + v1.w);
        s2b += (v1.x * v1.x + v1.y * v1.y) + (v1.z * v1.z + v1.w * v1.w);
        s1a += (v2.x + v2.y) + (v2.z + v2.w);
        s2a += (v2.x * v2.x + v2.y * v2.y) + (v2.z * v2.z + v2.w * v2.w);
        s1b += (v3.x + v3.y) + (v3.z + v3.w);
        s2b += (v3.x * v3.x + v3.y * v3.y) + (v3.z * v3.z + v3.w * v3.w);
    }

    // wave (64-lane) butterfly reduce in double
    double d1 = (double)s1a + (double)s1b;
    double d2 = (double)s2a + (double)s2b;
    #pragma unroll
    for (int off = 32; off > 0; off >>= 1) {
        d1 += __shfl_down(d1, off, 64);
        d2 += __shfl_down(d2, off, 64);
    }
    __shared__ double sh1[4], sh2[4];
    const int wave = threadIdx.x >> 6;
    if ((threadIdx.x & 63) == 0) { sh1[wave] = d1; sh2[wave] = d2; }
    __syncthreads();
    if (threadIdx.x == 0) {
        double t1 = (sh1[0] + sh1[1]) + (sh1[2] + sh1[3]);
        double t2 = (sh2[0] + sh2[1]) + (sh2[2] + sh2[3]);
        part[bc * BPC1 + blk] = make_double2(t1, t2);
    }
}

// ---------------- Kernel 2: partials -> stats -> MLP -> gate g[256] --------
__global__ __launch_bounds__(256) void cca_mlp(const double2* __restrict__ part,
                                               const float* __restrict__ w1,
                                               const float* __restrict__ b1,
                                               const float* __restrict__ w2,
                                               const float* __restrict__ b2,
                                               float* __restrict__ g) {
    __shared__ float y[NCH];          // [b][c]
    __shared__ float h[BATCH][4];
    const int t = threadIdx.x;        // one thread per channel (256)

    double s1 = 0.0, s2 = 0.0;
    #pragma unroll
    for (int k = 0; k < BPC1; ++k) {
        double2 pv = part[t * BPC1 + k];
        s1 += pv.x; s2 += pv.y;
    }
    double mean = s1 / (double)SPATIAL;
    double var  = s2 / (double)SPATIAL - mean * mean;
    if (var < 0.0) var = 0.0;
    y[t] = (float)(sqrt(var) + mean);
    __syncthreads();

    if (t < BATCH * 4) {              // 16 threads: h[b][r]
        const int b = t >> 2, r = t & 3;
        float acc = b1[r];
        #pragma unroll
        for (int c = 0; c < CCH; ++c) acc += w1[r * CCH + c] * y[b * CCH + c];
        h[b][r] = acc > 0.f ? acc : 0.f;
    }
    __syncthreads();

    {                                 // g[b][c] = sigmoid(w2[c,:] . h[b,:] + b2[c])
        const int b = t / CCH, c = t % CCH;
        float acc = b2[c];
        #pragma unroll
        for (int r = 0; r < 4; ++r) acc += w2[c * 4 + r] * h[b][r];
        g[t] = 1.f / (1.f + __expf(-acc));
    }
}

// ---------------- Kernel 3: out = x * g[bc] ----------------
// grid = NCH*BPC3 blocks x 256 threads. REVERSE traversal: first-dispatched
// blocks read the highest addresses of x -- the part the stats pass left in
// the Infinity Cache. Non-temporal stores keep the out stream from evicting x.
__global__ __launch_bounds__(256) void cca_scale(const float* __restrict__ x,
                                                 const float* __restrict__ g,
                                                 float* __restrict__ out) {
    const int gid = (int)gridDim.x - 1 - (int)blockIdx.x;
    const int bc  = gid / BPC3;
    const int blk = gid % BPC3;
    const float gv = g[bc];
    const size_t base = (size_t)bc * NVEC + (size_t)blk * (NVEC / BPC3)
                      + threadIdx.x;
    const vfloat4* xv = (const vfloat4*)x + base;
    vfloat4* ov = (vfloat4*)out + base;
    #pragma unroll
    for (int k = 0; k < 8; ++k) {
        vfloat4 v = xv[k * 256];
        v *= gv;
        __builtin_nontemporal_store(v, ov + k * 256);
    }
}

extern "C" void kernel_launch(void* const* d_in, const int* in_sizes, int n_in,
                              void* d_out, int out_size, void* d_ws, size_t ws_size,
                              hipStream_t stream) {
    const float* x  = (const float*)d_in[0];
    const float* w1 = (const float*)d_in[1];
    const float* b1 = (const float*)d_in[2];
    const float* w2 = (const float*)d_in[3];
    const float* b2 = (const float*)d_in[4];
    float* out = (float*)d_out;

    // ws layout: [0, 64K): double2 part[256][16]; [64K, 65K): float g[256]
    double2* part = (double2*)d_ws;
    float* g = (float*)((char*)d_ws + (size_t)NCH * BPC1 * sizeof(double2));

    cca_stats<<<NCH * BPC1, 256, 0, stream>>>(x, part);
    cca_mlp<<<1, 256, 0, stream>>>(part, w1, b1, w2, b2, g);
    cca_scale<<<NCH * BPC3, 256, 0, stream>>>(x, g, out);
}